// Round 1
// baseline (116.191 us; speedup 1.0000x reference)
//
#include <hip/hip_runtime.h>
#include <math.h>

#define SIZE 256
#define KV 64
#define KCONST 100000.0f
#define EPSC 1e-05f

// One thread per output pixel. Each block (256 threads) covers 256 pixels of
// exactly one image (65536 pixels/image, so blocks never straddle images).
__global__ __launch_bounds__(256) void contour_to_mask_kernel(
    const float* __restrict__ contour,  // (8, 64, 2) flattened
    float* __restrict__ out)            // (8, 256, 256) flattened
{
    __shared__ float2 sc[KV];

    const int gid = blockIdx.x * 256 + threadIdx.x;
    const int img = gid >> 16;          // gid / 65536
    const int p   = gid & 0xFFFF;       // pixel within image
    const int i   = p >> 8;
    const int j   = p & 0xFF;

    // Stage this image's contour into LDS (128 floats).
    if (threadIdx.x < 2 * KV) {
        ((float*)sc)[threadIdx.x] = contour[img * 2 * KV + threadIdx.x];
    }
    __syncthreads();

    const float mx = (float)i * (1.0f / SIZE);
    const float my = (float)j * (1.0f / SIZE);

    // diff[0]
    float dx = sc[0].x - mx;
    float dy = sc[0].y - my;
    float nd = sqrtf(dx * dx + dy * dy);   // ||diff[k]||, rolled forward

    float sum = 0.0f;

#pragma unroll 4
    for (int k = 0; k < KV; ++k) {
        const int k1 = (k + 1) & (KV - 1);
        const float nx = sc[k1].x - mx;
        const float ny = sc[k1].y - my;

        // sign = tanh(K * (dy*nx - dx*ny)); keep products un-fused to match
        // the reference's separate-multiply-then-subtract rounding.
        const float p1 = __fmul_rn(dy, nx);
        const float p2 = __fmul_rn(dx, ny);
        const float sgn = tanhf(KCONST * (p1 - p2));

        const float dot = dx * nx + dy * ny;
        const float nr  = sqrtf(nx * nx + ny * ny);

        float ratio = dot / (nd * nr);
        ratio = fminf(fmaxf(ratio, -1.0f + EPSC), 1.0f - EPSC);

        sum += sgn * acosf(ratio);

        dx = nx; dy = ny; nd = nr;
    }

    const float val = fabsf(sum * (1.0f / (2.0f * (float)M_PI)));
    out[gid] = fminf(val, 1.0f);
}

extern "C" void kernel_launch(void* const* d_in, const int* in_sizes, int n_in,
                              void* d_out, int out_size, void* d_ws, size_t ws_size,
                              hipStream_t stream) {
    const float* contour = (const float*)d_in[0];
    float* out = (float*)d_out;

    const int total = 8 * SIZE * SIZE;          // 524288 pixels
    const int blocks = total / 256;             // 2048 blocks
    contour_to_mask_kernel<<<blocks, 256, 0, stream>>>(contour, out);
}

// Round 2
// 78.370 us; speedup vs baseline: 1.4826x; 1.4826x over previous
//
#include <hip/hip_runtime.h>
#include <math.h>

#define SIZE 256
#define KV 64
#define EPSC 1e-05f

// tanh(100000*s) = 1 - 2/(exp(200000*s)+1) = 1 - 2*rcp(exp2(C*s)+1)
// C = 200000 * log2(e). Saturates exactly to +/-1 (exp2->inf / ->0).
__device__ __forceinline__ float tanh_K(float s) {
    const float C = 288539.00817779f;  // 2 * 100000 * log2(e)
    float e = __builtin_amdgcn_exp2f(C * s);
    return fmaf(-2.0f, __builtin_amdgcn_rcpf(e + 1.0f), 1.0f);
}

// Abramowitz-Stegun 4.4.45: acos(x) ~= sqrt(1-x)*P3(x) for x in [0,1],
// acos(-x) = pi - acos(x). Max abs error ~6.7e-5 rad.
__device__ __forceinline__ float fast_acos(float x) {
    float ax = fabsf(x);
    float p = fmaf(ax, -0.0187293f, 0.0742610f);
    p = fmaf(ax, p, -0.2121144f);
    p = fmaf(ax, p, 1.5707288f);
    float r = __builtin_amdgcn_sqrtf(1.0f - ax) * p;
    return (x >= 0.0f) ? r : ((float)M_PI - r);
}

// One thread per output pixel; each 256-thread block covers one image's rows.
__global__ __launch_bounds__(256) void contour_to_mask_kernel(
    const float* __restrict__ contour,  // (8, 64, 2)
    float* __restrict__ out)            // (8, 256, 256)
{
    __shared__ float2 sc[KV];

    const int gid = blockIdx.x * 256 + threadIdx.x;
    const int img = gid >> 16;
    const int p   = gid & 0xFFFF;
    const int i   = p >> 8;
    const int j   = p & 0xFF;

    if (threadIdx.x < 2 * KV) {
        ((float*)sc)[threadIdx.x] = contour[img * 2 * KV + threadIdx.x];
    }
    __syncthreads();

    const float mx = (float)i * (1.0f / SIZE);
    const float my = (float)j * (1.0f / SIZE);

    float dx = sc[0].x - mx;
    float dy = sc[0].y - my;
    float n2d = dx * dx + dy * dy;      // ||diff_k||^2, rolled forward

    float sum = 0.0f;

#pragma unroll 8
    for (int k = 0; k < KV; ++k) {
        const int k1 = (k + 1) & (KV - 1);
        const float nx = sc[k1].x - mx;
        const float ny = sc[k1].y - my;

        // cross = dy*nx - dx*ny, products kept un-fused (tanh arg is
        // sign-critical near 0 and reference rounds each product).
        const float p1 = __fmul_rn(dy, nx);
        const float p2 = __fmul_rn(dx, ny);
        const float sgn = tanh_K(p1 - p2);

        const float dot = fmaf(dx, nx, dy * ny);
        const float n2r = fmaf(nx, nx, ny * ny);

        // dot / (sqrt(n2d)*sqrt(n2r)) == dot * rsqrt(n2d*n2r)
        float ratio = dot * __builtin_amdgcn_rsqf(n2d * n2r);
        ratio = fminf(fmaxf(ratio, -1.0f + EPSC), 1.0f - EPSC);

        sum = fmaf(sgn, fast_acos(ratio), sum);

        dx = nx; dy = ny; n2d = n2r;
    }

    const float val = fabsf(sum * (1.0f / (2.0f * (float)M_PI)));
    out[gid] = fminf(val, 1.0f);
}

extern "C" void kernel_launch(void* const* d_in, const int* in_sizes, int n_in,
                              void* d_out, int out_size, void* d_ws, size_t ws_size,
                              hipStream_t stream) {
    const float* contour = (const float*)d_in[0];
    float* out = (float*)d_out;

    const int total = 8 * SIZE * SIZE;
    const int blocks = total / 256;
    contour_to_mask_kernel<<<blocks, 256, 0, stream>>>(contour, out);
}

// Round 3
// 73.461 us; speedup vs baseline: 1.5817x; 1.0668x over previous
//
#include <hip/hip_runtime.h>
#include <math.h>

#define SIZE 256
#define KV 64
#define EPSC 1e-05f
#define STHR 6.25e-05f   // |cross| above this => tanh(1e5*x) == +/-1 within 7e-6

// Exact-enough tanh(100000*s): 1 - 2*rcp(exp2(C*s)+1), C = 200000*log2(e).
// Saturates exactly to +/-1; accurate through s ~ 0 (the near-edge case).
__device__ __forceinline__ float tanh_K(float s) {
    const float C = 288539.00817779f;
    float e = __builtin_amdgcn_exp2f(C * s);
    return fmaf(-2.0f, __builtin_amdgcn_rcpf(e + 1.0f), 1.0f);
}

// Abramowitz-Stegun 4.4.45, max abs err ~6.7e-5 rad.
__device__ __forceinline__ float fast_acos(float x) {
    float ax = fabsf(x);
    float p = fmaf(ax, -0.0187293f, 0.0742610f);
    p = fmaf(ax, p, -0.2121144f);
    p = fmaf(ax, p, 1.5707288f);
    float r = __builtin_amdgcn_sqrtf(1.0f - ax) * p;
    return (x >= 0.0f) ? r : ((float)M_PI - r);
}

// Two j-adjacent pixels per thread: mx is shared, so nx, nx^2, dx*nx are
// computed once per pair. 262144 pairs -> 1024 blocks; each block stays
// inside one image (32768 pairs/image, 256 pairs/block).
__global__ __launch_bounds__(256) void contour_to_mask_kernel(
    const float* __restrict__ contour,  // (8, 64, 2)
    float* __restrict__ out)            // (8, 256, 256)
{
    __shared__ float2 sc[KV];

    const int gid = blockIdx.x * 256 + threadIdx.x;  // pair index
    const int img = gid >> 15;
    const int q   = gid & 32767;
    const int i   = q >> 7;
    const int j2  = (q & 127) << 1;

    if (threadIdx.x < 2 * KV) {
        ((float*)sc)[threadIdx.x] = contour[img * 2 * KV + threadIdx.x];
    }
    __syncthreads();

    const float mx  = (float)i * (1.0f / SIZE);
    const float my0 = (float)j2 * (1.0f / SIZE);
    const float my1 = (float)(j2 + 1) * (1.0f / SIZE);

    float dx  = sc[0].x - mx;        // shared between the pair
    float dy0 = sc[0].y - my0;
    float dy1 = sc[0].y - my1;
    const float dx2 = dx * dx;
    float n2d0 = fmaf(dy0, dy0, dx2);
    float n2d1 = fmaf(dy1, dy1, dx2);

    float sum0 = 0.0f, sum1 = 0.0f;

#pragma unroll 8
    for (int k = 0; k < KV; ++k) {
        const int k1 = (k + 1) & (KV - 1);
        const float nx  = sc[k1].x - mx;   // shared
        const float ny0 = sc[k1].y - my0;
        const float ny1 = sc[k1].y - my1;

        // cross products, un-fused rounding to match reference near zero
        const float s0 = __fmul_rn(dy0, nx) - __fmul_rn(dx, ny0);
        const float s1 = __fmul_rn(dy1, nx) - __fmul_rn(dx, ny1);

        // sign fast path: exp2+rcp only when some lane is near-collinear
        float sg0 = copysignf(1.0f, s0);
        float sg1 = copysignf(1.0f, s1);
        if (__any((fabsf(s0) < STHR) || (fabsf(s1) < STHR))) {
            sg0 = tanh_K(s0);
            sg1 = tanh_K(s1);
        }

        const float dxnx = dx * nx;        // shared
        const float dot0 = fmaf(dy0, ny0, dxnx);
        const float dot1 = fmaf(dy1, ny1, dxnx);
        const float nx2  = nx * nx;        // shared
        const float n2r0 = fmaf(ny0, ny0, nx2);
        const float n2r1 = fmaf(ny1, ny1, nx2);

        float r0 = dot0 * __builtin_amdgcn_rsqf(n2d0 * n2r0);
        float r1 = dot1 * __builtin_amdgcn_rsqf(n2d1 * n2r1);
        r0 = fminf(fmaxf(r0, -1.0f + EPSC), 1.0f - EPSC);
        r1 = fminf(fmaxf(r1, -1.0f + EPSC), 1.0f - EPSC);

        sum0 = fmaf(sg0, fast_acos(r0), sum0);
        sum1 = fmaf(sg1, fast_acos(r1), sum1);

        dx = nx; dy0 = ny0; dy1 = ny1; n2d0 = n2r0; n2d1 = n2r1;
    }

    const float inv2pi = 1.0f / (2.0f * (float)M_PI);
    const float v0 = fminf(fabsf(sum0 * inv2pi), 1.0f);
    const float v1 = fminf(fabsf(sum1 * inv2pi), 1.0f);
    ((float2*)out)[gid] = make_float2(v0, v1);
}

extern "C" void kernel_launch(void* const* d_in, const int* in_sizes, int n_in,
                              void* d_out, int out_size, void* d_ws, size_t ws_size,
                              hipStream_t stream) {
    const float* contour = (const float*)d_in[0];
    float* out = (float*)d_out;

    const int pairs = 8 * SIZE * SIZE / 2;   // 262144
    const int blocks = pairs / 256;          // 1024
    contour_to_mask_kernel<<<blocks, 256, 0, stream>>>(contour, out);
}

// Round 4
// 72.020 us; speedup vs baseline: 1.6133x; 1.0200x over previous
//
#include <hip/hip_runtime.h>
#include <math.h>

#define SIZE 256
#define KV 64
#define EPSC 1e-05f
#define STHR 6.25e-05f   // |cross| above this => tanh(1e5*x) == +/-1 within 7e-6

typedef float        v2f __attribute__((ext_vector_type(2)));
typedef int          v2i __attribute__((ext_vector_type(2)));
typedef unsigned int v2u __attribute__((ext_vector_type(2)));

// Exact-enough tanh(100000*s): 1 - 2*rcp(exp2(C*s)+1), C = 200000*log2(e).
__device__ __forceinline__ float tanh_K(float s) {
    const float C = 288539.00817779f;
    float e = __builtin_amdgcn_exp2f(C * s);
    return fmaf(-2.0f, __builtin_amdgcn_rcpf(e + 1.0f), 1.0f);
}

__device__ __forceinline__ v2f vabs(v2f x) {
    v2u u = __builtin_bit_cast(v2u, x) & 0x7FFFFFFFu;
    return __builtin_bit_cast(v2f, u);
}
__device__ __forceinline__ v2f vsign1(v2f x) {  // copysign(1.0f, x)
    v2u u = (__builtin_bit_cast(v2u, x) & 0x80000000u) | 0x3F800000u;
    return __builtin_bit_cast(v2f, u);
}
__device__ __forceinline__ v2f vrsq(v2f x) {
    v2f r; r.x = __builtin_amdgcn_rsqf(x.x); r.y = __builtin_amdgcn_rsqf(x.y);
    return r;
}
__device__ __forceinline__ v2f vsqrt(v2f x) {
    v2f r; r.x = __builtin_amdgcn_sqrtf(x.x); r.y = __builtin_amdgcn_sqrtf(x.y);
    return r;
}
__device__ __forceinline__ v2f vminv(v2f a, v2f b) { return __builtin_elementwise_min(a, b); }
__device__ __forceinline__ v2f vminf2(v2f a, float b) { v2f bb = {b, b}; return __builtin_elementwise_min(a, bb); }
__device__ __forceinline__ v2f vmaxf2(v2f a, float b) { v2f bb = {b, b}; return __builtin_elementwise_max(a, bb); }

// Abramowitz-Stegun 4.4.45 acos, vectorized; max abs err ~6.7e-5 rad.
__device__ __forceinline__ v2f vacos(v2f x) {
    v2f ax = vabs(x);
    v2f p = ax * -0.0187293f + 0.0742610f;
    p = ax * p + -0.2121144f;
    p = ax * p + 1.5707288f;
    v2f r = vsqrt(1.0f - ax) * p;
    v2f alt = (float)M_PI - r;
    v2i m = x < 0.0f;                      // elementwise: -1 / 0
    v2u mu = __builtin_bit_cast(v2u, m);
    v2u ru = __builtin_bit_cast(v2u, r);
    v2u au = __builtin_bit_cast(v2u, alt);
    return __builtin_bit_cast(v2f, (mu & au) | (~mu & ru));
}

// 4 j-adjacent pixels per thread as two v2f SIMD pairs (v_pk_* fp32 ops).
// 131072 threads -> 512 blocks; 64 blocks per image (no block straddles images).
__global__ __launch_bounds__(256) void contour_to_mask_kernel(
    const float* __restrict__ contour,  // (8, 64, 2)
    float* __restrict__ out)            // (8, 256, 256)
{
    __shared__ float2 sc[KV];

    const int tid = blockIdx.x * 256 + threadIdx.x;  // quad index
    const int img = tid >> 14;                       // 16384 quads/image
    const int q   = tid & 16383;
    const int i   = q >> 6;                          // 64 quads/row
    const int j0  = (q & 63) << 2;

    if (threadIdx.x < 2 * KV) {
        ((float*)sc)[threadIdx.x] = contour[img * 2 * KV + threadIdx.x];
    }
    __syncthreads();

    const float mx = (float)i * (1.0f / SIZE);
    const v2f myA = { (float)j0       * (1.0f / SIZE), (float)(j0 + 1) * (1.0f / SIZE) };
    const v2f myB = { (float)(j0 + 2) * (1.0f / SIZE), (float)(j0 + 3) * (1.0f / SIZE) };

    float dx  = sc[0].x - mx;           // shared x-diff for all 4 pixels
    v2f  dyA  = sc[0].y - myA;
    v2f  dyB  = sc[0].y - myB;
    const float dx2 = dx * dx;
    v2f n2dA = dyA * dyA + dx2;
    v2f n2dB = dyB * dyB + dx2;

    v2f sumA = {0.0f, 0.0f};
    v2f sumB = {0.0f, 0.0f};

#pragma unroll 8
    for (int k = 0; k < KV; ++k) {
        const int k1 = (k + 1) & (KV - 1);
        const float cx = sc[k1].x, cy = sc[k1].y;
        const float nx = cx - mx;       // shared
        v2f nyA = cy - myA;
        v2f nyB = cy - myB;

        v2f sA = dyA * nx - dx * nyA;   // cross products
        v2f sB = dyB * nx - dx * nyB;

        v2f sgA = vsign1(sA);
        v2f sgB = vsign1(sB);
        v2f mm = vminv(vabs(sA), vabs(sB));
        if (__any(fminf(mm.x, mm.y) < STHR)) {   // rare: near-collinear lane
            sgA.x = tanh_K(sA.x); sgA.y = tanh_K(sA.y);
            sgB.x = tanh_K(sB.x); sgB.y = tanh_K(sB.y);
        }

        const float dxnx = dx * nx;     // shared
        const float nx2  = nx * nx;     // shared
        v2f dotA = dyA * nyA + dxnx;
        v2f dotB = dyB * nyB + dxnx;
        v2f n2rA = nyA * nyA + nx2;
        v2f n2rB = nyB * nyB + nx2;

        v2f rA = dotA * vrsq(n2dA * n2rA);
        v2f rB = dotB * vrsq(n2dB * n2rB);
        rA = vminf2(vmaxf2(rA, -1.0f + EPSC), 1.0f - EPSC);
        rB = vminf2(vmaxf2(rB, -1.0f + EPSC), 1.0f - EPSC);

        sumA += sgA * vacos(rA);
        sumB += sgB * vacos(rB);

        dx = nx; dyA = nyA; dyB = nyB; n2dA = n2rA; n2dB = n2rB;
    }

    const float inv2pi = 0.15915494309189535f;
    v2f vA = vminf2(vabs(sumA * inv2pi), 1.0f);
    v2f vB = vminf2(vabs(sumB * inv2pi), 1.0f);
    float4 o; o.x = vA.x; o.y = vA.y; o.z = vB.x; o.w = vB.y;
    ((float4*)out)[tid] = o;
}

extern "C" void kernel_launch(void* const* d_in, const int* in_sizes, int n_in,
                              void* d_out, int out_size, void* d_ws, size_t ws_size,
                              hipStream_t stream) {
    const float* contour = (const float*)d_in[0];
    float* out = (float*)d_out;

    const int quads = 8 * SIZE * SIZE / 4;   // 131072
    const int blocks = quads / 256;          // 512
    contour_to_mask_kernel<<<blocks, 256, 0, stream>>>(contour, out);
}

// Round 5
// 65.358 us; speedup vs baseline: 1.7778x; 1.1019x over previous
//
#include <hip/hip_runtime.h>
#include <math.h>

#define SIZE 256
#define KV 64
#define EPSC 1e-05f
#define STHR 6.0e-05f   // |cross| below this => tanh(1e5*x) not fully saturated

// tanh(100000*s) = 1 - 2*rcp(exp2(C*s)+1), C = 200000*log2(e). Exact +/-1 saturation.
__device__ __forceinline__ float tanh_K(float s) {
    const float C = 288539.00817779f;
    float e = __builtin_amdgcn_exp2f(C * s);
    return fmaf(-2.0f, __builtin_amdgcn_rcpf(e + 1.0f), 1.0f);
}

// Abramowitz-Stegun 4.4.45, max abs err ~6.7e-5 rad (only used on rare near-edge terms).
__device__ __forceinline__ float fast_acos(float x) {
    float ax = fabsf(x);
    float p = fmaf(ax, -0.0187293f, 0.0742610f);
    p = fmaf(ax, p, -0.2121144f);
    p = fmaf(ax, p, 1.5707288f);
    float r = __builtin_amdgcn_sqrtf(1.0f - ax) * p;
    return (x >= 0.0f) ? r : ((float)M_PI - r);
}

// Exact per-term correction for a near-edge (pixel,k): the reference's
// tanh(s)*acos term minus the sign(s)*theta the winding identity counted.
__device__ __forceinline__ void slow_fix(const float2* sc, int k, int k1,
                                         float mx, float my, float s_main,
                                         float& corr) {
    float2 c0 = sc[k], c1 = sc[k1];
    float dx = c0.x - mx, dy = c0.y - my;
    float nx = c1.x - mx, ny = c1.y - my;
    // reference-rounding cross for the tanh argument
    float se = __fmul_rn(dy, nx) - __fmul_rn(dx, ny);
    float dot = fmaf(dx, nx, dy * ny);
    float n2  = fmaf(dx, dx, dy * dy) * fmaf(nx, nx, ny * ny);
    float r = dot * __builtin_amdgcn_rsqf(n2);
    r = fminf(fmaxf(r, -1.0f + EPSC), 1.0f - EPSC);
    float th = fast_acos(r);
    float sgn = (s_main < 0.0f) ? -1.0f : 1.0f;   // must match crossing decision
    corr += (tanh_K(se) - sgn) * th;
}

// Winding number by crossing counting. Per (pixel,k):
//   s = dy*nx - dx*ny = A_k + mx*ey_k - my*ex_k   (A,ex,ey per-segment consts)
//   up-crossing  (cky<=my<ck1y) with s<0  -> wn++
//   down-crossing(ck1y<=my<cky) with s>=0 -> wn--
// Sum of reference angle terms == -2*pi*wn + corrections for near-edge terms.
__global__ __launch_bounds__(256) void contour_to_mask_kernel(
    const float* __restrict__ contour,  // (8, 64, 2)
    float* __restrict__ out)            // (8, 256, 256)
{
    __shared__ float2 sc[KV];      // raw contour (slow path)
    __shared__ float4 cons[KV];    // {A, ex, ey, c_{k+1}.y}

    const int gid = blockIdx.x * 256 + threadIdx.x;  // pixel-pair index
    const int img = gid >> 15;                       // 32768 pairs/image
    const int q   = gid & 32767;
    const int i   = q >> 7;                          // 128 pairs/row
    const int j0  = (q & 127) << 1;

    const float* cbase = contour + img * 2 * KV;
    if (threadIdx.x < 2 * KV) {
        ((float*)sc)[threadIdx.x] = cbase[threadIdx.x];
    }
    if (threadIdx.x < KV) {
        const int k  = threadIdx.x;
        const int k1 = (k + 1) & (KV - 1);
        float ckx = cbase[2 * k],      cky = cbase[2 * k + 1];
        float c1x = cbase[2 * k1],     c1y = cbase[2 * k1 + 1];
        float A  = cky * c1x - ckx * c1y;
        cons[k] = make_float4(A, c1x - ckx, c1y - cky, c1y);
    }
    __syncthreads();

    const float mx  = (float)i * (1.0f / SIZE);
    const float my0 = (float)j0 * (1.0f / SIZE);
    const float my1 = my0 + (1.0f / SIZE);

    int wn0 = 0, wn1 = 0;
    float corr0 = 0.0f, corr1 = 0.0f;
    bool gt0 = sc[0].y > my0;
    bool gt1 = sc[0].y > my1;

#pragma unroll 4
    for (int k = 0; k < KV; ++k) {
        const float4 cn = cons[k];   // broadcast ds_read_b128
        const float s0 = fmaf(mx, cn.z, fmaf(-my0, cn.y, cn.x));
        const float s1 = fmaf(mx, cn.z, fmaf(-my1, cn.y, cn.x));
        const bool gtn0 = cn.w > my0;
        const bool gtn1 = cn.w > my1;
        const bool neg0 = s0 < 0.0f;
        const bool neg1 = s1 < 0.0f;

        wn0 += (int)(!gt0 && gtn0 && neg0) - (int)(gt0 && !gtn0 && !neg0);
        wn1 += (int)(!gt1 && gtn1 && neg1) - (int)(gt1 && !gtn1 && !neg1);

        const bool near0 = fabsf(s0) < STHR;
        const bool near1 = fabsf(s1) < STHR;
        if (__any(near0 || near1)) {         // rare: ~2-3 of 64 iters per wave
            const int k1 = (k + 1) & (KV - 1);
            if (near0) slow_fix(sc, k, k1, mx, my0, s0, corr0);
            if (near1) slow_fix(sc, k, k1, mx, my1, s1, corr1);
        }
        gt0 = gtn0; gt1 = gtn1;
    }

    const float TWO_PI = 6.2831853071795865f;
    const float inv2pi = 0.15915494309189535f;
    float v0 = fminf(fabsf(fmaf(-TWO_PI, (float)wn0, corr0)) * inv2pi, 1.0f);
    float v1 = fminf(fabsf(fmaf(-TWO_PI, (float)wn1, corr1)) * inv2pi, 1.0f);
    ((float2*)out)[gid] = make_float2(v0, v1);
}

extern "C" void kernel_launch(void* const* d_in, const int* in_sizes, int n_in,
                              void* d_out, int out_size, void* d_ws, size_t ws_size,
                              hipStream_t stream) {
    const float* contour = (const float*)d_in[0];
    float* out = (float*)d_out;

    const int pairs = 8 * SIZE * SIZE / 2;   // 262144
    const int blocks = pairs / 256;          // 1024
    contour_to_mask_kernel<<<blocks, 256, 0, stream>>>(contour, out);
}

// Round 6
// 55.614 us; speedup vs baseline: 2.0892x; 1.1752x over previous
//
#include <hip/hip_runtime.h>
#include <math.h>

#define SIZE 256
#define KV 64
#define EPSC 1e-05f
#define STHR 6.0e-05f
#define SL_EPS 4e-09f

// tanh(100000*s) = 1 - 2*rcp(exp2(C*s)+1), C = 200000*log2(e).
__device__ __forceinline__ float tanh_K(float s) {
    const float C = 288539.00817779f;
    float e = __builtin_amdgcn_exp2f(C * s);
    return fmaf(-2.0f, __builtin_amdgcn_rcpf(e + 1.0f), 1.0f);
}

// Abramowitz-Stegun 4.4.45, max abs err ~6.7e-5 rad (rare path only).
__device__ __forceinline__ float fast_acos(float x) {
    float ax = fabsf(x);
    float p = fmaf(ax, -0.0187293f, 0.0742610f);
    p = fmaf(ax, p, -0.2121144f);
    p = fmaf(ax, p, 1.5707288f);
    float r = __builtin_amdgcn_sqrtf(1.0f - ax) * p;
    return (x >= 0.0f) ? r : ((float)M_PI - r);
}

// (tanh(se) - sgn) * theta for one (pixel, segment); sgn must be the sign
// convention the crossing count used for this (pixel, segment).
__device__ __forceinline__ float corr_term(float2 c0, float2 c1,
                                           float mx, float my, float sgn) {
    float dx = c0.x - mx, dy = c0.y - my;
    float nx = c1.x - mx, ny = c1.y - my;
    float se = __fmul_rn(dy, nx) - __fmul_rn(dx, ny);   // reference rounding
    float dot = fmaf(dx, nx, dy * ny);
    float n2 = fmaf(dx, dx, dy * dy) * fmaf(nx, nx, ny * ny);
    float r = dot * __builtin_amdgcn_rsqf(n2);
    r = fminf(fmaxf(r, -1.0f + EPSC), 1.0f - EPSC);
    return (tanh_K(se) - sgn) * fast_acos(r);
}

// One wave per column (fixed i => fixed mx); lane k handles segment k.
// Crossing contributions are j-intervals -> LDS difference array -> scan.
__global__ __launch_bounds__(256) void contour_to_mask_kernel(
    const float* __restrict__ contour,  // (8, 64, 2)
    float* __restrict__ out)            // (8, 256, 256)
{
    __shared__ float2 sc[KV];
    __shared__ float4 cons[KV];                               // A, ex, ey, -
    __shared__ __attribute__((aligned(16))) int   diffA[4][272];
    __shared__ __attribute__((aligned(16))) float corrA[4][256];
    __shared__ int wcnt[4];
    __shared__ int wlist[4][32];

    const int wave = threadIdx.x >> 6;
    const int lane = threadIdx.x & 63;
    const int img  = blockIdx.x >> 6;            // 64 blocks per image
    const int col  = ((blockIdx.x & 63) << 2) + wave;
    const float mx = (float)col * (1.0f / SIZE);

    const float* cbase = contour + img * 2 * KV;
    if (threadIdx.x < 2 * KV)
        ((float*)sc)[threadIdx.x] = cbase[threadIdx.x];
    __syncthreads();
    if (threadIdx.x < KV) {
        int k = threadIdx.x, k1 = (k + 1) & (KV - 1);
        float ckx = sc[k].x, cky = sc[k].y;
        float c1x = sc[k1].x, c1y = sc[k1].y;
        cons[k] = make_float4(cky * c1x - ckx * c1y, c1x - ckx, c1y - cky, 0.0f);
    }
    int*   diff = diffA[wave];
    float* corr = corrA[wave];
#pragma unroll
    for (int t = 0; t < 4; ++t) { diff[lane + 64 * t] = 0; corr[lane + 64 * t] = 0.0f; }
    if (lane == 0) { diff[256] = 0; wcnt[wave] = 0; }
    __syncthreads();

    // ---- per-segment interval pass ----
    {
        const int k = lane, k1 = (k + 1) & (KV - 1);
        const float4 cn = cons[k];
        const float A = cn.x, ey = cn.z;
        const float cky = sc[k].y, c1y = sc[k1].y;
        const float s0 = fmaf(mx, ey, A);
        const float sl = cn.y * (1.0f / SIZE);     // s(j) = s0 - j*sl

        const int y0 = (int)ceilf((float)SIZE * cky);  // j>=y0 <=> my>=cky (exact)
        const int y1 = (int)ceilf((float)SIZE * c1y);

        int nlo, nhi;              // {s<0} = [nlo, nhi)
        bool wide = false;
        int bl = 0, bh = 0;
        const float asl = fabsf(sl);
        if (asl >= SL_EPS) {
            const float jst = s0 / sl;             // s-root in j
            const float jc = fminf(fmaxf(jst, -2.0e6f), 2.0e6f);
            if (sl > 0.0f) {                       // s decreasing: s<0 <=> j>jst
                nlo = max(0, min(SIZE, (int)floorf(jc) + 1)); nhi = SIZE;
            } else {                               // s increasing: s<0 <=> j<jst
                nlo = 0; nhi = max(0, min(SIZE, (int)ceilf(jc)));
            }
            const float wband = STHR / asl;        // band half-width in j
            const float blo = jst - wband, bhi = jst + wband;
            if (bhi > -1.0f && blo < (float)SIZE) {
                if (wband > 6.0f) wide = true;
                else { bl = max(0, (int)floorf(blo));
                       bh = min(SIZE, (int)ceilf(bhi) + 1); }
            }
        } else {                                   // s ~ constant along column
            nlo = 0; nhi = (s0 < 0.0f) ? SIZE : 0;
            if (fabsf(s0) < STHR + 2.0e-6f) wide = true;
        }

        // up-crossings [y0,y1) ∩ {s<0}; down-crossings [y1,y0) ∩ {s>=0}
        int ua = max(y0, nlo), ub = min(y1, nhi);
        if (ua < ub) { atomicAdd(&diff[ua], 1); atomicAdd(&diff[ub], -1); }
        int clo, chi;                              // complement of [nlo,nhi)
        if (nlo == 0) { clo = nhi; chi = SIZE; } else { clo = 0; chi = nlo; }
        int da = max(y1, clo), db = min(y0, chi);
        if (da < db) { atomicAdd(&diff[da], -1); atomicAdd(&diff[db], 1); }

        if (wide) {
            int idx = atomicAdd(&wcnt[wave], 1);
            if (idx < 32) wlist[wave][idx] = k | (nlo << 6) | (nhi << 15);
        } else if (bl < bh) {                      // <=15 near-band pixels
            const float2 c0 = sc[k], c1 = sc[k1];
            for (int j = bl; j < bh; ++j) {
                float sj = fmaf(-(float)j, sl, s0);
                if (fabsf(sj) < 4.0f * STHR) {
                    float my = (float)j * (1.0f / SIZE);
                    float sgn = (j >= nlo && j < nhi) ? -1.0f : 1.0f;
                    atomicAdd(&corr[j], corr_term(c0, c1, mx, my, sgn));
                }
            }
        }
    }
    __syncthreads();

    // ---- wide-band segments: per-pixel corrections (rare) ----
    {
        const int nw = min(wcnt[wave], 32);
        for (int t = 0; t < nw; ++t) {
            const int e = wlist[wave][t];
            const int k = e & 63;
            const int nlo = (e >> 6) & 511, nhi = (e >> 15) & 511;
            const int k1 = (k + 1) & (KV - 1);
            const float4 cn = cons[k];
            const float s0 = fmaf(mx, cn.z, cn.x);
            const float sl = cn.y * (1.0f / SIZE);
            const float2 c0 = sc[k], c1 = sc[k1];
#pragma unroll
            for (int u = 0; u < 4; ++u) {
                const int j = 4 * lane + u;
                const float sj = fmaf(-(float)j, sl, s0);
                if (fabsf(sj) < STHR) {
                    const float my = (float)j * (1.0f / SIZE);
                    const float sgn = (j >= nlo && j < nhi) ? -1.0f : 1.0f;
                    corr[j] += corr_term(c0, c1, mx, my, sgn);
                }
            }
        }
    }
    __syncthreads();

    // ---- prefix scan of diff -> winding number; finalize 4 pixels/lane ----
    const int4   dq = ((const int4*)diff)[lane];
    const float4 cq = ((const float4*)corr)[lane];
    const int p0 = dq.x;
    const int p1 = p0 + dq.y;
    const int p2 = p1 + dq.z;
    const int p3 = p2 + dq.w;
    int scan = p3;
#pragma unroll
    for (int d = 1; d < 64; d <<= 1) {
        int up = __shfl_up(scan, d, 64);
        if (lane >= d) scan += up;
    }
    const int excl = scan - p3;

    const float TWO_PI = 6.283185307179586f;
    const float inv2pi = 0.15915494309189535f;
    float4 o;
    o.x = fminf(fabsf(fmaf(-TWO_PI, (float)(excl + p0), cq.x)) * inv2pi, 1.0f);
    o.y = fminf(fabsf(fmaf(-TWO_PI, (float)(excl + p1), cq.y)) * inv2pi, 1.0f);
    o.z = fminf(fabsf(fmaf(-TWO_PI, (float)(excl + p2), cq.z)) * inv2pi, 1.0f);
    o.w = fminf(fabsf(fmaf(-TWO_PI, (float)(excl + p3), cq.w)) * inv2pi, 1.0f);
    ((float4*)out)[img * 16384 + col * 64 + lane] = o;
}

extern "C" void kernel_launch(void* const* d_in, const int* in_sizes, int n_in,
                              void* d_out, int out_size, void* d_ws, size_t ws_size,
                              hipStream_t stream) {
    const float* contour = (const float*)d_in[0];
    float* out = (float*)d_out;
    // 8 images x 256 columns, 4 columns (waves) per block
    contour_to_mask_kernel<<<512, 256, 0, stream>>>(contour, out);
}

// Round 7
// 54.750 us; speedup vs baseline: 2.1222x; 1.0158x over previous
//
#include <hip/hip_runtime.h>
#include <math.h>

#define SIZE 256
#define KV 64
#define EPSC 1e-05f
#define STHR 6.0e-05f
#define SL_EPS 4e-09f

// tanh(100000*s) = 1 - 2*rcp(exp2(C*s)+1), C = 200000*log2(e).
__device__ __forceinline__ float tanh_K(float s) {
    const float C = 288539.00817779f;
    float e = __builtin_amdgcn_exp2f(C * s);
    return fmaf(-2.0f, __builtin_amdgcn_rcpf(e + 1.0f), 1.0f);
}

// Abramowitz-Stegun 4.4.45, max abs err ~6.7e-5 rad (rare path only).
__device__ __forceinline__ float fast_acos(float x) {
    float ax = fabsf(x);
    float p = fmaf(ax, -0.0187293f, 0.0742610f);
    p = fmaf(ax, p, -0.2121144f);
    p = fmaf(ax, p, 1.5707288f);
    float r = __builtin_amdgcn_sqrtf(1.0f - ax) * p;
    return (x >= 0.0f) ? r : ((float)M_PI - r);
}

// (tanh(se) - sgn) * theta for one (pixel, segment); sgn must match the
// sign convention the crossing count used for this (pixel, segment).
__device__ __forceinline__ float corr_term(float2 c0, float2 c1,
                                           float mx, float my, float sgn) {
    float dx = c0.x - mx, dy = c0.y - my;
    float nx = c1.x - mx, ny = c1.y - my;
    float se = __fmul_rn(dy, nx) - __fmul_rn(dx, ny);   // reference rounding
    float dot = fmaf(dx, nx, dy * ny);
    float n2 = fmaf(dx, dx, dy * dy) * fmaf(nx, nx, ny * ny);
    float r = dot * __builtin_amdgcn_rsqf(n2);
    r = fminf(fmaxf(r, -1.0f + EPSC), 1.0f - EPSC);
    return (tanh_K(se) - sgn) * fast_acos(r);
}

// One wave = one block = one column. Lane k handles segment k. Crossing
// contributions are j-intervals -> LDS difference array -> wave scan.
// Single-wave blocks: all barriers are intra-wave (near-free), no cross-wave
// phase alignment, wide-segment list via ballot+shfl instead of LDS atomics.
__global__ __launch_bounds__(64) void contour_to_mask_kernel(
    const float* __restrict__ contour,  // (8, 64, 2)
    float* __restrict__ out)            // (8, 256, 256)
{
    __shared__ float2 sc[KV];
    __shared__ __attribute__((aligned(16))) int   diff[272];
    __shared__ __attribute__((aligned(16))) float corr[256];

    const int lane = threadIdx.x;
    const int img  = blockIdx.x >> 8;
    const int col  = blockIdx.x & 255;
    const float mx = (float)col * (1.0f / SIZE);

    sc[lane] = ((const float2*)(contour + img * 2 * KV))[lane];
#pragma unroll
    for (int t = 0; t < 4; ++t) { diff[lane + 64 * t] = 0; corr[lane + 64 * t] = 0.0f; }
    if (lane < 16) diff[256 + lane] = 0;
    __syncthreads();   // single-wave: ~waitcnt only

    // ---- per-segment constants (registers, lane k owns segment k) ----
    const int k1 = (lane + 1) & (KV - 1);
    const float2 c0 = sc[lane], c1 = sc[k1];
    const float A  = c0.y * c1.x - c0.x * c1.y;
    const float ex = c1.x - c0.x;
    const float ey = c1.y - c0.y;
    const float s0 = fmaf(mx, ey, A);
    const float sl = ex * (1.0f / SIZE);           // s(j) = s0 - j*sl

    const int y0 = (int)ceilf((float)SIZE * c0.y); // j>=y0 <=> my>=cky (exact)
    const int y1 = (int)ceilf((float)SIZE * c1.y);

    int nlo, nhi;                 // {s<0} = [nlo, nhi)
    bool wide = false;
    int bl = 0, bh = 0;
    const float asl = fabsf(sl);
    if (asl >= SL_EPS) {
        const float jst = s0 / sl;
        const float jc = fminf(fmaxf(jst, -2.0e6f), 2.0e6f);
        if (sl > 0.0f) { nlo = max(0, min(SIZE, (int)floorf(jc) + 1)); nhi = SIZE; }
        else           { nlo = 0; nhi = max(0, min(SIZE, (int)ceilf(jc))); }
        const float wband = STHR / asl;
        const float blo = jst - wband, bhi = jst + wband;
        if (bhi > -1.0f && blo < (float)SIZE) {
            if (wband > 6.0f) wide = true;
            else { bl = max(0, (int)floorf(blo)); bh = min(SIZE, (int)ceilf(bhi) + 1); }
        }
    } else {
        nlo = 0; nhi = (s0 < 0.0f) ? SIZE : 0;
        if (fabsf(s0) < STHR + 2.0e-6f) wide = true;
    }

    // up-crossings [y0,y1) ∩ {s<0}; down-crossings [y1,y0) ∩ {s>=0}
    {
        int ua = max(y0, nlo), ub = min(y1, nhi);
        if (ua < ub) { atomicAdd(&diff[ua], 1); atomicAdd(&diff[ub], -1); }
        int clo, chi;
        if (nlo == 0) { clo = nhi; chi = SIZE; } else { clo = 0; chi = nlo; }
        int da = max(y1, clo), db = min(y0, chi);
        if (da < db) { atomicAdd(&diff[da], -1); atomicAdd(&diff[db], 1); }
    }

    // narrow near-band pixels: serial per owning lane (<=15), rare
    if (!wide && bl < bh) {
        for (int j = bl; j < bh; ++j) {
            float sj = fmaf(-(float)j, sl, s0);
            if (fabsf(sj) < 4.0f * STHR) {
                float my = (float)j * (1.0f / SIZE);
                float sgn = (j >= nlo && j < nhi) ? -1.0f : 1.0f;
                atomicAdd(&corr[j], corr_term(c0, c1, mx, my, sgn));
            }
        }
    }

    // wide-band segments: all 64 lanes sweep 4 pixels each (ballot+shfl)
    unsigned long long wmask = __ballot(wide);
    while (wmask) {
        const int k = __ffsll(wmask) - 1;
        wmask &= wmask - 1;
        const float s0k = __shfl(s0, k);
        const float slk = __shfl(sl, k);
        const int nlok = __shfl(nlo, k);
        const int nhik = __shfl(nhi, k);
        const float2 ck0 = sc[k], ck1 = sc[(k + 1) & (KV - 1)];
#pragma unroll
        for (int u = 0; u < 4; ++u) {
            const int j = 4 * lane + u;
            const float sj = fmaf(-(float)j, slk, s0k);
            if (fabsf(sj) < STHR) {
                const float my = (float)j * (1.0f / SIZE);
                const float sgn = (j >= nlok && j < nhik) ? -1.0f : 1.0f;
                atomicAdd(&corr[j], corr_term(ck0, ck1, mx, my, sgn));
            }
        }
    }
    __syncthreads();

    // ---- prefix scan of diff -> winding number; finalize 4 pixels/lane ----
    const int4   dq = ((const int4*)diff)[lane];
    const float4 cq = ((const float4*)corr)[lane];
    const int p0 = dq.x;
    const int p1 = p0 + dq.y;
    const int p2 = p1 + dq.z;
    const int p3 = p2 + dq.w;
    int scan = p3;
#pragma unroll
    for (int d = 1; d < 64; d <<= 1) {
        int up = __shfl_up(scan, d, 64);
        if (lane >= d) scan += up;
    }
    const int excl = scan - p3;

    const float TWO_PI = 6.283185307179586f;
    const float inv2pi = 0.15915494309189535f;
    float4 o;
    o.x = fminf(fabsf(fmaf(-TWO_PI, (float)(excl + p0), cq.x)) * inv2pi, 1.0f);
    o.y = fminf(fabsf(fmaf(-TWO_PI, (float)(excl + p1), cq.y)) * inv2pi, 1.0f);
    o.z = fminf(fabsf(fmaf(-TWO_PI, (float)(excl + p2), cq.z)) * inv2pi, 1.0f);
    o.w = fminf(fabsf(fmaf(-TWO_PI, (float)(excl + p3), cq.w)) * inv2pi, 1.0f);
    ((float4*)out)[img * 16384 + col * 64 + lane] = o;
}

extern "C" void kernel_launch(void* const* d_in, const int* in_sizes, int n_in,
                              void* d_out, int out_size, void* d_ws, size_t ws_size,
                              hipStream_t stream) {
    const float* contour = (const float*)d_in[0];
    float* out = (float*)d_out;
    // 8 images x 256 columns, one wave (64-thread block) per column
    contour_to_mask_kernel<<<2048, 64, 0, stream>>>(contour, out);
}